// Round 10
// baseline (85.343 us; speedup 1.0000x reference)
//
#include <hip/hip_runtime.h>

#define HWQ  4096      // H*W = 64*64
#define NCAM 6
#define IMH  32
#define IMW  88
#define NPIX (IMH*IMW) // 2816

typedef unsigned short ushort_t;
typedef unsigned int   uint_t;
typedef __fp16 h2   __attribute__((ext_vector_type(2)));
typedef __fp16 f16x8 __attribute__((ext_vector_type(8)));
typedef float  f32x4 __attribute__((ext_vector_type(4)));

union UH { uint_t u; h2 h; };
__device__ inline h2 u2h(uint_t x){ UH c; c.u = x; return c.h; }
__device__ inline uint_t packrtz(float a, float b){
    UH c; c.h = __builtin_amdgcn_cvt_pkrtz(a, b); return c.u;
}

// butterfly add, VALU-only (DPP)
#define DPPADD(s, ctrl) { \
    int _x = __builtin_amdgcn_update_dpp(0, __float_as_int(s), ctrl, 0xF, 0xF, true); \
    s += __int_as_float(_x); }

// ---------------------------------------------------------------------------
// Fused producer kernel: blocks 0..527 = KV MFMA GEMM, 528..1039 = BEV MLPs.
// The two populations have complementary bottlenecks (MFMA/HBM vs VALU/LDS)
// and co-schedule across CUs in one launch.  Shared LDS arena, aliased.
// ---------------------------------------------------------------------------
__global__ __launch_bounds__(256) void prep_kernel(
    // kv args
    const float* __restrict__ wkv, const float* __restrict__ img,
    const float* __restrict__ bkv, ushort_t* __restrict__ kvb,
    // bev args
    const float* __restrict__ bev,
    const float* __restrict__ wq,    const float* __restrict__ bq,
    const float* __restrict__ woff1, const float* __restrict__ boff1,
    const float* __restrict__ woff2, const float* __restrict__ boff2,
    const float* __restrict__ Ein,   const float* __restrict__ Kin,
    const float* __restrict__ wxy,
    ushort_t* __restrict__ qb, uint4* __restrict__ sampbuf)
{
    __shared__ __align__(16) char smem[56320];
    const int bid = blockIdx.x;
    const int t = threadIdx.x;

    if (bid < 528) {
        // ===================== KV path =====================
        // LDS: Al [128][40] u16 @0 (10240 B); Bl [128][40] u16 @10240;
        //      St [128][140] u16 @20480 (35840 B)
        auto Al = reinterpret_cast<ushort_t (*)[40]>(smem);
        auto Bl = reinterpret_cast<ushort_t (*)[40]>(smem + 10240);
        auto St = reinterpret_cast<ushort_t (*)[140]>(smem + 20480);

        const int bx = (bid % 22) * 128;      // px0
        const int y  = (bid / 22) & 1;        // ch half
        const int z  = bid / 44;              // slice
        const int lane = t & 63, wid = t >> 6;
        const int wr = wid >> 1, wc = wid & 1;
        const int srow = t >> 1, spart = t & 1;
        const int grA = (srow < 64) ? (y * 64 + srow) : (64 + y * 64 + srow);
        const int tp  = t >> 4;               // k-pair id (0..15)
        const int pxs = t & 15;               // px phase
        const float* imgz = img + (size_t)z * 128 * NPIX;

        f32x4 zero4 = {0.f, 0.f, 0.f, 0.f};
        f32x4 acc[4][4];
        #pragma unroll
        for (int i = 0; i < 4; ++i)
            #pragma unroll
            for (int j = 0; j < 4; ++j) acc[i][j] = zero4;

        for (int k0 = 0; k0 < 128; k0 += 32) {
            const float* ap = &wkv[(size_t)grA * 128 + k0 + spart * 16];
            float4 a0 = *(const float4*)(ap+0), a1 = *(const float4*)(ap+4);
            float4 a2 = *(const float4*)(ap+8), a3 = *(const float4*)(ap+12);
            uint4 w0, w1;
            w0.x = packrtz(a0.x,a0.y); w0.y = packrtz(a0.z,a0.w);
            w0.z = packrtz(a1.x,a1.y); w0.w = packrtz(a1.z,a1.w);
            w1.x = packrtz(a2.x,a2.y); w1.y = packrtz(a2.z,a2.w);
            w1.z = packrtz(a3.x,a3.y); w1.w = packrtz(a3.z,a3.w);
            *(uint4*)&Al[srow][spart*16]     = w0;
            *(uint4*)&Al[srow][spart*16 + 8] = w1;
            {
                const float* r0p = imgz + (size_t)(k0 + 2*tp) * NPIX + bx + pxs;
                const float* r1p = r0p + NPIX;
                #pragma unroll
                for (int j = 0; j < 8; ++j) {
                    float av = r0p[16*j], cv = r1p[16*j];
                    *(uint_t*)&Bl[pxs + 16*j][2*tp] = packrtz(av, cv);
                }
            }
            __syncthreads();
            f16x8 af[4], bf[4];
            #pragma unroll
            for (int mi = 0; mi < 4; ++mi)
                af[mi] = *(const f16x8*)&Al[wr*64 + mi*16 + (lane & 15)][(lane >> 4) * 8];
            #pragma unroll
            for (int ni = 0; ni < 4; ++ni)
                bf[ni] = *(const f16x8*)&Bl[wc*64 + ni*16 + (lane & 15)][(lane >> 4) * 8];
            #pragma unroll
            for (int mi = 0; mi < 4; ++mi)
                #pragma unroll
                for (int ni = 0; ni < 4; ++ni)
                    acc[mi][ni] = __builtin_amdgcn_mfma_f32_16x16x32_f16(af[mi], bf[ni], acc[mi][ni], 0, 0, 0);
            __syncthreads();
        }

        #pragma unroll
        for (int mi = 0; mi < 4; ++mi) {
            int m0  = wr * 64 + mi * 16 + (lane >> 4) * 4;
            int gm0 = (m0 < 64) ? (y * 64 + m0) : (64 + y * 64 + m0);
            float4 bsv = *(const float4*)&bkv[gm0];
            int off0 = (m0 < 64) ? (2 * m0) : (2 * (m0 - 64) + 2);
            #pragma unroll
            for (int ni = 0; ni < 4; ++ni) {
                int pxl = wc * 64 + ni * 16 + (lane & 15);
                f32x4 d = acc[mi][ni];
                *(uint_t*)&St[pxl][off0]     = packrtz(d.x + bsv.x, d.y + bsv.y);
                *(uint_t*)&St[pxl][off0 + 4] = packrtz(d.z + bsv.z, d.w + bsv.w);
            }
        }
        __syncthreads();
        #pragma unroll
        for (int it = 0; it < 8; ++it) {
            int idx = t + it * 256;
            int px = idx >> 4, c16 = idx & 15;
            uint4 v = *(const uint4*)&St[px][c16 * 8];
            *(uint4*)&kvb[((size_t)z * NPIX + bx + px) * 256 + y * 128 + c16 * 8] = v;
        }
    } else {
        // ===================== BEV path =====================
        // LDS: bevS f32[128][20] @0 (10240); Ws f32[32][260] @10240 (33280);
        //      o1S f32[128][20] @43520 (10240); offS f32[16][16] @53760 (1024)
        auto bevS = reinterpret_cast<float (*)[20]>(smem);
        auto Ws   = reinterpret_cast<float (*)[260]>(smem + 10240);
        auto o1S  = reinterpret_cast<float (*)[20]>(smem + 43520);
        auto offS = reinterpret_cast<float (*)[16]>(smem + 53760);

        const int qg0 = (bid - 528) * 16;
        const int b   = qg0 >> 12;
        const int hw0 = qg0 & 4095;

        #pragma unroll
        for (int i = 0; i < 2; ++i) {
            int f4 = t + i * 256;
            int ch = f4 >> 2, part = f4 & 3;
            float4 v = *(const float4*)&bev[((size_t)b * 128 + ch) * 4096 + hw0 + part * 4];
            *(float4*)&bevS[ch][part * 4] = v;
        }
        const float* wrow = (t < 128) ? (wq + (size_t)t * 128) : (woff1 + (size_t)(t - 128) * 128);

        const int og = t >> 2, pxg = t & 3;
        float acc[4][4] = {};
        for (int k0 = 0; k0 < 128; k0 += 32) {
            __syncthreads();
            #pragma unroll
            for (int i = 0; i < 8; ++i) {
                float4 wv = *(const float4*)&wrow[k0 + i * 4];
                Ws[i*4+0][t] = wv.x; Ws[i*4+1][t] = wv.y;
                Ws[i*4+2][t] = wv.z; Ws[i*4+3][t] = wv.w;
            }
            __syncthreads();
            #pragma unroll
            for (int kk = 0; kk < 32; ++kk) {
                float4 w4 = *(const float4*)&Ws[kk][og * 4];
                float4 b4 = *(const float4*)&bevS[k0 + kk][pxg * 4];
                float wa[4] = {w4.x, w4.y, w4.z, w4.w};
                float ba[4] = {b4.x, b4.y, b4.z, b4.w};
                #pragma unroll
                for (int i = 0; i < 4; ++i)
                    #pragma unroll
                    for (int j = 0; j < 4; ++j) acc[i][j] += wa[i] * ba[j];
            }
        }
        __syncthreads();
        if (og < 32) {
            int ch = og * 4;
            float4 bqv = *(const float4*)&bq[ch];
            #pragma unroll
            for (int j = 0; j < 4; ++j) {
                int px = pxg * 4 + j;
                uint_t u0 = packrtz(acc[0][j] + bqv.x, acc[1][j] + bqv.y);
                uint_t u1 = packrtz(acc[2][j] + bqv.z, acc[3][j] + bqv.w);
                *(uint2*)&qb[(size_t)(qg0 + px) * 128 + ch] = make_uint2(u0, u1);
            }
        } else {
            int ch = og * 4 - 128;
            float bov[4] = {boff1[ch], boff1[ch+1], boff1[ch+2], boff1[ch+3]};
            #pragma unroll
            for (int i = 0; i < 4; ++i)
                #pragma unroll
                for (int j = 0; j < 4; ++j)
                    o1S[ch + i][pxg * 4 + j] = fmaxf(acc[i][j] + bov[i], 0.f);
        }
        __syncthreads();
        {
            int o = t >> 4, px = t & 15;
            const float* w2 = woff2 + (size_t)o * 128;
            float s = boff2[o];
            for (int k = 0; k < 128; k += 4) {
                float4 wv = *(const float4*)&w2[k];
                s += wv.x * o1S[k][px]   + wv.y * o1S[k+1][px]
                   + wv.z * o1S[k+2][px] + wv.w * o1S[k+3][px];
            }
            offS[px][o] = s;
        }
        __syncthreads();
        if (t < 96) {
            int n = t >> 4, px = t & 15;
            int hw = hw0 + px;
            float wx = wxy[hw], wy = wxy[4096 + hw];
            const float* e  = Ein + (size_t)(b * 6 + n) * 16;
            const float* km = Kin + (size_t)(b * 6 + n) * 9;
            float c0 = e[0]*wx + e[1]*wy + e[3];
            float c1 = e[4]*wx + e[5]*wy + e[7];
            float c2 = e[8]*wx + e[9]*wy + e[11];
            float pxx = km[0]*c0 + km[1]*c1 + km[2]*c2;
            float pyy = km[3]*c0 + km[4]*c1 + km[5]*c2;
            float pzz = fmaxf(km[6]*c0 + km[7]*c1 + km[8]*c2, 1e-6f);
            float rz = 1.f / pzz;
            float gx = pxx * rz * (2.f / 87.f) - 1.f;
            float gy = pyy * rz * (2.f / 31.f) - 1.f;
            uint4* drow = sampbuf + (size_t)(qg0 + px) * 48 + n * 8;
            #pragma unroll
            for (int p = 0; p < 8; ++p) {
                float sx = fminf(fmaxf(gx + offS[px][2*p],     -1.f), 1.f);
                float sy = fminf(fmaxf(gy + offS[px][2*p + 1], -1.f), 1.f);
                float ixf = fminf((sx + 1.f) * 43.5f, 86.99994f);   // x0 <= 86
                float iyf = fminf((sy + 1.f) * 15.5f, 30.99998f);   // y0 <= 30
                float x0f = floorf(ixf), y0f = floorf(iyf);
                float fx = ixf - x0f, fy = iyf - y0f;
                float gxw = 1.f - fx, gyw = 1.f - fy;
                uint4 rec;
                rec.x = packrtz(gxw * gyw, fx * gyw);   // {w00, w01}
                rec.y = packrtz(gxw * fy,  fx * fy);    // {w10, w11}
                rec.z = (uint_t)((int)(y0f * 88.f + x0f) * 512);
                rec.w = 0;
                drow[p] = rec;
            }
        }
    }
}

// ---------------------------------------------------------------------------
// Attention, camera-affinity. Grid = 1536 x 512. XCD x gets tasks {3x..3x+2}
// (task = (slice, query-half)) -> <=2 camera slices (2.9 MB) per XCD L2.
// Block = 1 slice x 32 queries; lane = 16*qi + c; lane owns 8 channels.
// ---------------------------------------------------------------------------
__global__ __launch_bounds__(512, 4) void attn_kernel(
    const ushort_t* __restrict__ kvb,     // [12][NPIX][256] f16 interleaved
    const ushort_t* __restrict__ qb,      // [qg][128] f16
    const uint4*    __restrict__ sampbuf, // [qg][48]
    ushort_t* __restrict__ wbuf2)         // [12][4096][128] f16 partials
{
    __shared__ uint4 recS[256];           // 32 queries x 8 recs (this camera)
    const int bid = blockIdx.x;
    const int x   = bid & 7;
    const int k   = bid >> 3;             // 0..191
    const int task = x * 3 + (k >> 6);    // 0..23
    const int s    = task >> 1;           // slice 0..11
    const int b    = (s >= 6) ? 1 : 0;
    const int n    = s - b * 6;
    const int ql0  = (task & 1) * 2048 + (k & 63) * 32;

    const int t    = threadIdx.x;
    const int lane = t & 63;
    const int w    = t >> 6;
    const int qi   = lane >> 4;
    const int c    = lane & 15;
    const int q_l  = w * 4 + qi;
    const int qg   = b * 4096 + ql0 + q_l;

    if (t < 256)
        recS[t] = sampbuf[(size_t)(b * 4096 + ql0 + (t >> 3)) * 48 + n * 8 + (t & 7)];

    const uint4 Q = *(const uint4*)&qb[(size_t)qg * 128 + c * 8];
    const h2 q01 = u2h(Q.x), q23 = u2h(Q.y), q45 = u2h(Q.z), q67 = u2h(Q.w);
    __syncthreads();

    const char* cb = (const char*)kvb + (size_t)s * NPIX * 512 + c * 32;

    float ssum = 0.f;
    float vac0 = 0.f, vac1 = 0.f, vac2 = 0.f, vac3 = 0.f;
    float vac4 = 0.f, vac5 = 0.f, vac6 = 0.f, vac7 = 0.f;

    #pragma unroll 2
    for (int p = 0; p < 8; ++p) {
        uint4 rec = recS[q_l * 8 + p];
        h2 wA = u2h(rec.x), wB = u2h(rec.y);
        h2 w00 = {wA.x, wA.x}, w01 = {wA.y, wA.y};
        h2 w10 = {wB.x, wB.x}, w11 = {wB.y, wB.y};
        const char* r = cb + rec.z;
        uint4 t00a = *(const uint4*)(r);
        uint4 t00b = *(const uint4*)(r + 16);
        uint4 t01a = *(const uint4*)(r + 512);
        uint4 t01b = *(const uint4*)(r + 528);
        uint4 t10a = *(const uint4*)(r + 45056);
        uint4 t10b = *(const uint4*)(r + 45072);
        uint4 t11a = *(const uint4*)(r + 45568);
        uint4 t11b = *(const uint4*)(r + 45584);

        h2 kb01 = u2h(t00a.x)*w00 + u2h(t01a.x)*w01 + u2h(t10a.x)*w10 + u2h(t11a.x)*w11;
        h2 kb23 = u2h(t00a.z)*w00 + u2h(t01a.z)*w01 + u2h(t10a.z)*w10 + u2h(t11a.z)*w11;
        h2 kb45 = u2h(t00b.x)*w00 + u2h(t01b.x)*w01 + u2h(t10b.x)*w10 + u2h(t11b.x)*w11;
        h2 kb67 = u2h(t00b.z)*w00 + u2h(t01b.z)*w01 + u2h(t10b.z)*w10 + u2h(t11b.z)*w11;
        h2 vb01 = u2h(t00a.y)*w00 + u2h(t01a.y)*w01 + u2h(t10a.y)*w10 + u2h(t11a.y)*w11;
        h2 vb23 = u2h(t00a.w)*w00 + u2h(t01a.w)*w01 + u2h(t10a.w)*w10 + u2h(t11a.w)*w11;
        h2 vb45 = u2h(t00b.y)*w00 + u2h(t01b.y)*w01 + u2h(t10b.y)*w10 + u2h(t11b.y)*w11;
        h2 vb67 = u2h(t00b.w)*w00 + u2h(t01b.w)*w01 + u2h(t10b.w)*w10 + u2h(t11b.w)*w11;

#if __has_builtin(__builtin_amdgcn_fdot2)
        float sd = __builtin_amdgcn_fdot2(q01, kb01,
                    __builtin_amdgcn_fdot2(q23, kb23,
                     __builtin_amdgcn_fdot2(q45, kb45,
                      __builtin_amdgcn_fdot2(q67, kb67, 0.f, false), false), false), false);
#else
        float sd = (float)q01.x*(float)kb01.x + (float)q01.y*(float)kb01.y
                 + (float)q23.x*(float)kb23.x + (float)q23.y*(float)kb23.y
                 + (float)q45.x*(float)kb45.x + (float)q45.y*(float)kb45.y
                 + (float)q67.x*(float)kb67.x + (float)q67.y*(float)kb67.y;
#endif
        DPPADD(sd, 0xB1);   // quad xor1
        DPPADD(sd, 0x4E);   // quad xor2  -> head's 4-lane sum
        float es = __expf(sd);
        ssum += es;
        vac0 += es * (float)vb01.x; vac1 += es * (float)vb01.y;
        vac2 += es * (float)vb23.x; vac3 += es * (float)vb23.y;
        vac4 += es * (float)vb45.x; vac5 += es * (float)vb45.y;
        vac6 += es * (float)vb67.x; vac7 += es * (float)vb67.y;
    }
    const float inv = 1.f / (ssum * (float)NCAM);
    uint4 o;
    o.x = packrtz(vac0 * inv, vac1 * inv);
    o.y = packrtz(vac2 * inv, vac3 * inv);
    o.z = packrtz(vac4 * inv, vac5 * inv);
    o.w = packrtz(vac6 * inv, vac7 * inv);
    *(uint4*)&wbuf2[((size_t)s * 4096 + ql0 + q_l) * 128 + c * 8] = o;
}

// ---------------------------------------------------------------------------
// Output projection with 6-camera partial sum in the B^T stage.
// ---------------------------------------------------------------------------
__global__ __launch_bounds__(256) void sgemm_kernel(
    const float* __restrict__ A, const ushort_t* __restrict__ B2,
    const float* __restrict__ bias, float* __restrict__ C)
{
    __shared__ float As[16][68];
    __shared__ float Bs[16][68];
    const int z = blockIdx.z;
    float* Cb = C + (size_t)z * 128 * 4096;
    const int tid = threadIdx.x;
    const int bm = blockIdx.y * 64, bn = blockIdx.x * 64;
    const int tm = ((tid >> 4) & 15) << 2;
    const int tn = (tid & 15) << 2;

    float acc[4][4] = {};
    for (int k0 = 0; k0 < 128; k0 += 16) {
        #pragma unroll
        for (int i = 0; i < 4; ++i) {
            int idx = tid + i * 256;
            int mk = idx >> 4, kk = idx & 15;
            As[kk][mk] = A[(size_t)(bm + mk) * 128 + (k0 + kk)];
        }
        {
            int pxl = tid >> 2, kc = (tid & 3) * 4;
            float b0 = 0.f, b1 = 0.f, b2 = 0.f, b3 = 0.f;
            #pragma unroll
            for (int nn = 0; nn < 6; ++nn) {
                const ushort_t* src = B2 + (((size_t)(z*6+nn) * 4096 + bn + pxl) * 128 + k0 + kc);
                uint2 v = *(const uint2*)src;
                h2 h0 = u2h(v.x), h1 = u2h(v.y);
                b0 += (float)h0.x; b1 += (float)h0.y;
                b2 += (float)h1.x; b3 += (float)h1.y;
            }
            Bs[kc+0][pxl] = b0; Bs[kc+1][pxl] = b1;
            Bs[kc+2][pxl] = b2; Bs[kc+3][pxl] = b3;
        }
        __syncthreads();
        #pragma unroll
        for (int kk = 0; kk < 16; ++kk) {
            const float4 av = *(const float4*)&As[kk][tm];
            const float4 bv = *(const float4*)&Bs[kk][tn];
            const float a[4]  = {av.x, av.y, av.z, av.w};
            const float bb[4] = {bv.x, bv.y, bv.z, bv.w};
            #pragma unroll
            for (int i = 0; i < 4; ++i)
                #pragma unroll
                for (int j = 0; j < 4; ++j) acc[i][j] += a[i] * bb[j];
        }
        __syncthreads();
    }
    #pragma unroll
    for (int i = 0; i < 4; ++i) {
        int gm = bm + tm + i;
        float bi = bias[gm];
        float4 v = make_float4(acc[i][0]+bi, acc[i][1]+bi, acc[i][2]+bi, acc[i][3]+bi);
        *(float4*)&Cb[(size_t)gm * 4096 + (bn + tn)] = v;
    }
}

// ---------------------------------------------------------------------------
extern "C" void kernel_launch(void* const* d_in, const int* in_sizes, int n_in,
                              void* d_out, int out_size, void* d_ws, size_t ws_size,
                              hipStream_t stream)
{
    const float* bev   = (const float*)d_in[0];
    const float* img   = (const float*)d_in[1];
    const float* Kin   = (const float*)d_in[2];
    const float* Ein   = (const float*)d_in[3];
    const float* wxy   = (const float*)d_in[4];
    const float* wq    = (const float*)d_in[5];
    const float* bq    = (const float*)d_in[6];
    const float* wkv   = (const float*)d_in[7];
    const float* bkv   = (const float*)d_in[8];
    const float* woff1 = (const float*)d_in[9];
    const float* boff1 = (const float*)d_in[10];
    const float* woff2 = (const float*)d_in[11];
    const float* boff2 = (const float*)d_in[12];
    const float* wproj = (const float*)d_in[13];
    const float* bproj = (const float*)d_in[14];
    float* out = (float*)d_out;

    char* wsb = (char*)d_ws;
    ushort_t* kvb   = (ushort_t*)wsb;                       // 17,301,504 B
    ushort_t* qbb   = (ushort_t*)(wsb + 17301504);          //  2,097,152 B
    uint4*    sampb = (uint4*)   (wsb + 19398656);          //  6,291,456 B
    ushort_t* wbuf2 = (ushort_t*)(wsb + 25690112);          // 12,582,912 B

    prep_kernel<<<dim3(1040), 256, 0, stream>>>(
        wkv, img, bkv, kvb,
        bev, wq, bq, woff1, boff1, woff2, boff2, Ein, Kin, wxy, qbb, sampb);
    attn_kernel<<<dim3(1536), 512, 0, stream>>>(kvb, qbb, sampb, wbuf2);
    sgemm_kernel<<<dim3(HWQ/64, 2, 2), 256, 0, stream>>>(wproj, wbuf2, bproj, out);
}

// Round 11
// 74.655 us; speedup vs baseline: 1.1432x; 1.1432x over previous
//
#include <hip/hip_runtime.h>

#define HWQ  4096      // H*W = 64*64
#define NCAM 6
#define IMH  32
#define IMW  88
#define NPIX (IMH*IMW) // 2816

typedef unsigned short ushort_t;
typedef unsigned int   uint_t;
typedef __fp16 h2   __attribute__((ext_vector_type(2)));
typedef __fp16 f16x8 __attribute__((ext_vector_type(8)));
typedef float  f32x4 __attribute__((ext_vector_type(4)));

union UH { uint_t u; h2 h; };
__device__ inline h2 u2h(uint_t x){ UH c; c.u = x; return c.h; }
__device__ inline uint_t packrtz(float a, float b){
    UH c; c.h = __builtin_amdgcn_cvt_pkrtz(a, b); return c.u;
}

// butterfly add, VALU-only (DPP)
#define DPPADD(s, ctrl) { \
    int _x = __builtin_amdgcn_update_dpp(0, __float_as_int(s), ctrl, 0xF, 0xF, true); \
    s += __int_as_float(_x); }

// ---------------------------------------------------------------------------
// KV 1x1 conv via f16 MFMA, img-transpose fused into B staging.
// LDS: Al+Bl (20.5 KB, k-loop) aliased by St (35.8 KB, epilogue) -> 35.8 KB
// total -> 3-4 blocks/CU (was 2).
// Row layout (u16[256] per pixel): [k2t,k2t+1,v2t,v2t+1] at 4t.
// ---------------------------------------------------------------------------
__global__ __launch_bounds__(256, 3) void kv_mfma(
    const float* __restrict__ wkv, const float* __restrict__ img,
    const float* __restrict__ bias, ushort_t* __restrict__ kvb)
{
    __shared__ __align__(16) char smem[35840];
    auto Al = reinterpret_cast<ushort_t (*)[40]>(smem);            // [128][40]
    auto Bl = reinterpret_cast<ushort_t (*)[40]>(smem + 10240);    // [128][40]
    auto St = reinterpret_cast<ushort_t (*)[140]>(smem);           // [128][140] (alias)

    const int t = threadIdx.x;
    const int bx = (blockIdx.x % 22) * 128;   // px0
    const int y  = (blockIdx.x / 22) & 1;     // ch half
    const int z  = blockIdx.x / 44;           // slice
    const int lane = t & 63, wid = t >> 6;
    const int wr = wid >> 1, wc = wid & 1;
    const int srow = t >> 1, spart = t & 1;
    const int grA = (srow < 64) ? (y * 64 + srow) : (64 + y * 64 + srow);
    const int tp  = t >> 4;               // k-pair id (0..15)
    const int pxs = t & 15;               // px phase
    const float* imgz = img + (size_t)z * 128 * NPIX;

    f32x4 zero4 = {0.f, 0.f, 0.f, 0.f};
    f32x4 acc[4][4];
    #pragma unroll
    for (int i = 0; i < 4; ++i)
        #pragma unroll
        for (int j = 0; j < 4; ++j) acc[i][j] = zero4;

    for (int k0 = 0; k0 < 128; k0 += 32) {
        const float* ap = &wkv[(size_t)grA * 128 + k0 + spart * 16];
        float4 a0 = *(const float4*)(ap+0), a1 = *(const float4*)(ap+4);
        float4 a2 = *(const float4*)(ap+8), a3 = *(const float4*)(ap+12);
        uint4 w0, w1;
        w0.x = packrtz(a0.x,a0.y); w0.y = packrtz(a0.z,a0.w);
        w0.z = packrtz(a1.x,a1.y); w0.w = packrtz(a1.z,a1.w);
        w1.x = packrtz(a2.x,a2.y); w1.y = packrtz(a2.z,a2.w);
        w1.z = packrtz(a3.x,a3.y); w1.w = packrtz(a3.z,a3.w);
        *(uint4*)&Al[srow][spart*16]     = w0;
        *(uint4*)&Al[srow][spart*16 + 8] = w1;
        {
            const float* r0p = imgz + (size_t)(k0 + 2*tp) * NPIX + bx + pxs;
            const float* r1p = r0p + NPIX;
            #pragma unroll
            for (int j = 0; j < 8; ++j) {
                float av = r0p[16*j], cv = r1p[16*j];
                *(uint_t*)&Bl[pxs + 16*j][2*tp] = packrtz(av, cv);
            }
        }
        __syncthreads();
        f16x8 af[4], bf[4];
        #pragma unroll
        for (int mi = 0; mi < 4; ++mi)
            af[mi] = *(const f16x8*)&Al[wr*64 + mi*16 + (lane & 15)][(lane >> 4) * 8];
        #pragma unroll
        for (int ni = 0; ni < 4; ++ni)
            bf[ni] = *(const f16x8*)&Bl[wc*64 + ni*16 + (lane & 15)][(lane >> 4) * 8];
        #pragma unroll
        for (int mi = 0; mi < 4; ++mi)
            #pragma unroll
            for (int ni = 0; ni < 4; ++ni)
                acc[mi][ni] = __builtin_amdgcn_mfma_f32_16x16x32_f16(af[mi], bf[ni], acc[mi][ni], 0, 0, 0);
        __syncthreads();   // also protects the St alias below
    }

    // ---- epilogue: stage interleaved rows in St (aliases Al/Bl), store ----
    #pragma unroll
    for (int mi = 0; mi < 4; ++mi) {
        int m0  = wr * 64 + mi * 16 + (lane >> 4) * 4;
        int gm0 = (m0 < 64) ? (y * 64 + m0) : (64 + y * 64 + m0);
        float4 bsv = *(const float4*)&bias[gm0];
        int off0 = (m0 < 64) ? (2 * m0) : (2 * (m0 - 64) + 2);
        #pragma unroll
        for (int ni = 0; ni < 4; ++ni) {
            int pxl = wc * 64 + ni * 16 + (lane & 15);
            f32x4 d = acc[mi][ni];
            *(uint_t*)&St[pxl][off0]     = packrtz(d.x + bsv.x, d.y + bsv.y);
            *(uint_t*)&St[pxl][off0 + 4] = packrtz(d.z + bsv.z, d.w + bsv.w);
        }
    }
    __syncthreads();
    #pragma unroll
    for (int it = 0; it < 8; ++it) {
        int idx = t + it * 256;
        int px = idx >> 4, c16 = idx & 15;
        uint4 v = *(const uint4*)&St[px][c16 * 8];
        *(uint4*)&kvb[((size_t)z * NPIX + bx + px) * 256 + y * 128 + c16 * 8] = v;
    }
}

// ---------------------------------------------------------------------------
// Fused BEV-side: q-proj (f16), offset MLP, camera projection, sample records.
// LDS diet: W staged in 16-row chunks (16.6 KB), o1S aliases bevS (written
// only after the k-loop) -> 27.3 KB total -> 4 blocks/CU (was 2).
// ---------------------------------------------------------------------------
__global__ __launch_bounds__(256, 4) void bev_mlp(
    const float* __restrict__ bev,
    const float* __restrict__ wq,    const float* __restrict__ bq,
    const float* __restrict__ woff1, const float* __restrict__ boff1,
    const float* __restrict__ woff2, const float* __restrict__ boff2,
    const float* __restrict__ Ein,   const float* __restrict__ Kin,
    const float* __restrict__ wxy,
    ushort_t* __restrict__ qb, uint4* __restrict__ sampbuf)
{
    __shared__ __align__(16) char smem[27904];
    auto bevS = reinterpret_cast<float (*)[20]>(smem);             // [128][20]
    auto o1S  = reinterpret_cast<float (*)[20]>(smem);             // alias of bevS
    auto Ws   = reinterpret_cast<float (*)[260]>(smem + 10240);    // [16][260]
    auto offS = reinterpret_cast<float (*)[16]>(smem + 26880);     // [16][16]

    const int t = threadIdx.x;
    const int qg0 = blockIdx.x * 16;
    const int b   = qg0 >> 12;
    const int hw0 = qg0 & 4095;

    #pragma unroll
    for (int i = 0; i < 2; ++i) {
        int f4 = t + i * 256;
        int ch = f4 >> 2, part = f4 & 3;
        float4 v = *(const float4*)&bev[((size_t)b * 128 + ch) * 4096 + hw0 + part * 4];
        *(float4*)&bevS[ch][part * 4] = v;
    }
    const float* wrow = (t < 128) ? (wq + (size_t)t * 128) : (woff1 + (size_t)(t - 128) * 128);

    const int og = t >> 2, pxg = t & 3;
    float acc[4][4] = {};
    for (int k0 = 0; k0 < 128; k0 += 16) {
        __syncthreads();
        #pragma unroll
        for (int i = 0; i < 4; ++i) {          // stage W^T chunk (16 k-rows)
            float4 wv = *(const float4*)&wrow[k0 + i * 4];
            Ws[i*4+0][t] = wv.x; Ws[i*4+1][t] = wv.y;
            Ws[i*4+2][t] = wv.z; Ws[i*4+3][t] = wv.w;
        }
        __syncthreads();
        #pragma unroll
        for (int kk = 0; kk < 16; ++kk) {
            float4 w4 = *(const float4*)&Ws[kk][og * 4];
            float4 b4 = *(const float4*)&bevS[k0 + kk][pxg * 4];
            float wa[4] = {w4.x, w4.y, w4.z, w4.w};
            float ba[4] = {b4.x, b4.y, b4.z, b4.w};
            #pragma unroll
            for (int i = 0; i < 4; ++i)
                #pragma unroll
                for (int j = 0; j < 4; ++j) acc[i][j] += wa[i] * ba[j];
        }
    }
    __syncthreads();   // all bevS reads done -> o1S alias is safe below
    if (og < 32) {
        int ch = og * 4;
        float4 bqv = *(const float4*)&bq[ch];
        #pragma unroll
        for (int j = 0; j < 4; ++j) {
            int px = pxg * 4 + j;
            uint_t u0 = packrtz(acc[0][j] + bqv.x, acc[1][j] + bqv.y);
            uint_t u1 = packrtz(acc[2][j] + bqv.z, acc[3][j] + bqv.w);
            *(uint2*)&qb[(size_t)(qg0 + px) * 128 + ch] = make_uint2(u0, u1);
        }
    } else {
        int ch = og * 4 - 128;
        float bov[4] = {boff1[ch], boff1[ch+1], boff1[ch+2], boff1[ch+3]};
        #pragma unroll
        for (int i = 0; i < 4; ++i)
            #pragma unroll
            for (int j = 0; j < 4; ++j)
                o1S[ch + i][pxg * 4 + j] = fmaxf(acc[i][j] + bov[i], 0.f);
    }
    __syncthreads();
    {
        int o = t >> 4, px = t & 15;
        const float* w2 = woff2 + (size_t)o * 128;
        float s = boff2[o];
        for (int k = 0; k < 128; k += 4) {
            float4 wv = *(const float4*)&w2[k];
            s += wv.x * o1S[k][px]   + wv.y * o1S[k+1][px]
               + wv.z * o1S[k+2][px] + wv.w * o1S[k+3][px];
        }
        offS[px][o] = s;
    }
    __syncthreads();
    if (t < 96) {
        int n = t >> 4, px = t & 15;
        int hw = hw0 + px;
        float wx = wxy[hw], wy = wxy[4096 + hw];
        const float* e  = Ein + (size_t)(b * 6 + n) * 16;
        const float* km = Kin + (size_t)(b * 6 + n) * 9;
        float c0 = e[0]*wx + e[1]*wy + e[3];
        float c1 = e[4]*wx + e[5]*wy + e[7];
        float c2 = e[8]*wx + e[9]*wy + e[11];
        float pxx = km[0]*c0 + km[1]*c1 + km[2]*c2;
        float pyy = km[3]*c0 + km[4]*c1 + km[5]*c2;
        float pzz = fmaxf(km[6]*c0 + km[7]*c1 + km[8]*c2, 1e-6f);
        float rz = 1.f / pzz;
        float gx = pxx * rz * (2.f / 87.f) - 1.f;
        float gy = pyy * rz * (2.f / 31.f) - 1.f;
        uint4* drow = sampbuf + (size_t)(qg0 + px) * 48 + n * 8;
        #pragma unroll
        for (int p = 0; p < 8; ++p) {
            float sx = fminf(fmaxf(gx + offS[px][2*p],     -1.f), 1.f);
            float sy = fminf(fmaxf(gy + offS[px][2*p + 1], -1.f), 1.f);
            float ixf = fminf((sx + 1.f) * 43.5f, 86.99994f);   // x0 <= 86
            float iyf = fminf((sy + 1.f) * 15.5f, 30.99998f);   // y0 <= 30
            float x0f = floorf(ixf), y0f = floorf(iyf);
            float fx = ixf - x0f, fy = iyf - y0f;
            float gxw = 1.f - fx, gyw = 1.f - fy;
            uint4 rec;
            rec.x = packrtz(gxw * gyw, fx * gyw);   // {w00, w01}
            rec.y = packrtz(gxw * fy,  fx * fy);    // {w10, w11}
            rec.z = (uint_t)((int)(y0f * 88.f + x0f) * 512);
            rec.w = 0;
            drow[p] = rec;
        }
    }
}

// ---------------------------------------------------------------------------
// Attention, camera-affinity. Grid = 1536 x 512. XCD x gets tasks {3x..3x+2}
// (task = (slice, query-half)) -> <=2 camera slices (2.9 MB) per XCD L2.
// Block = 1 slice x 32 queries; lane = 16*qi + c; lane owns 8 channels.
// ---------------------------------------------------------------------------
__global__ __launch_bounds__(512, 4) void attn_kernel(
    const ushort_t* __restrict__ kvb,     // [12][NPIX][256] f16 interleaved
    const ushort_t* __restrict__ qb,      // [qg][128] f16
    const uint4*    __restrict__ sampbuf, // [qg][48]
    ushort_t* __restrict__ wbuf2)         // [12][4096][128] f16 partials
{
    __shared__ uint4 recS[256];           // 32 queries x 8 recs (this camera)
    const int bid = blockIdx.x;
    const int x   = bid & 7;
    const int k   = bid >> 3;             // 0..191
    const int task = x * 3 + (k >> 6);    // 0..23
    const int s    = task >> 1;           // slice 0..11
    const int b    = (s >= 6) ? 1 : 0;
    const int n    = s - b * 6;
    const int ql0  = (task & 1) * 2048 + (k & 63) * 32;

    const int t    = threadIdx.x;
    const int lane = t & 63;
    const int w    = t >> 6;
    const int qi   = lane >> 4;
    const int c    = lane & 15;
    const int q_l  = w * 4 + qi;
    const int qg   = b * 4096 + ql0 + q_l;

    if (t < 256)
        recS[t] = sampbuf[(size_t)(b * 4096 + ql0 + (t >> 3)) * 48 + n * 8 + (t & 7)];

    const uint4 Q = *(const uint4*)&qb[(size_t)qg * 128 + c * 8];
    const h2 q01 = u2h(Q.x), q23 = u2h(Q.y), q45 = u2h(Q.z), q67 = u2h(Q.w);
    __syncthreads();

    const char* cb = (const char*)kvb + (size_t)s * NPIX * 512 + c * 32;

    float ssum = 0.f;
    float vac0 = 0.f, vac1 = 0.f, vac2 = 0.f, vac3 = 0.f;
    float vac4 = 0.f, vac5 = 0.f, vac6 = 0.f, vac7 = 0.f;

    #pragma unroll 2
    for (int p = 0; p < 8; ++p) {
        uint4 rec = recS[q_l * 8 + p];
        h2 wA = u2h(rec.x), wB = u2h(rec.y);
        h2 w00 = {wA.x, wA.x}, w01 = {wA.y, wA.y};
        h2 w10 = {wB.x, wB.x}, w11 = {wB.y, wB.y};
        const char* r = cb + rec.z;
        uint4 t00a = *(const uint4*)(r);
        uint4 t00b = *(const uint4*)(r + 16);
        uint4 t01a = *(const uint4*)(r + 512);
        uint4 t01b = *(const uint4*)(r + 528);
        uint4 t10a = *(const uint4*)(r + 45056);
        uint4 t10b = *(const uint4*)(r + 45072);
        uint4 t11a = *(const uint4*)(r + 45568);
        uint4 t11b = *(const uint4*)(r + 45584);

        h2 kb01 = u2h(t00a.x)*w00 + u2h(t01a.x)*w01 + u2h(t10a.x)*w10 + u2h(t11a.x)*w11;
        h2 kb23 = u2h(t00a.z)*w00 + u2h(t01a.z)*w01 + u2h(t10a.z)*w10 + u2h(t11a.z)*w11;
        h2 kb45 = u2h(t00b.x)*w00 + u2h(t01b.x)*w01 + u2h(t10b.x)*w10 + u2h(t11b.x)*w11;
        h2 kb67 = u2h(t00b.z)*w00 + u2h(t01b.z)*w01 + u2h(t10b.z)*w10 + u2h(t11b.z)*w11;
        h2 vb01 = u2h(t00a.y)*w00 + u2h(t01a.y)*w01 + u2h(t10a.y)*w10 + u2h(t11a.y)*w11;
        h2 vb23 = u2h(t00a.w)*w00 + u2h(t01a.w)*w01 + u2h(t10a.w)*w10 + u2h(t11a.w)*w11;
        h2 vb45 = u2h(t00b.y)*w00 + u2h(t01b.y)*w01 + u2h(t10b.y)*w10 + u2h(t11b.y)*w11;
        h2 vb67 = u2h(t00b.w)*w00 + u2h(t01b.w)*w01 + u2h(t10b.w)*w10 + u2h(t11b.w)*w11;

#if __has_builtin(__builtin_amdgcn_fdot2)
        float sd = __builtin_amdgcn_fdot2(q01, kb01,
                    __builtin_amdgcn_fdot2(q23, kb23,
                     __builtin_amdgcn_fdot2(q45, kb45,
                      __builtin_amdgcn_fdot2(q67, kb67, 0.f, false), false), false), false);
#else
        float sd = (float)q01.x*(float)kb01.x + (float)q01.y*(float)kb01.y
                 + (float)q23.x*(float)kb23.x + (float)q23.y*(float)kb23.y
                 + (float)q45.x*(float)kb45.x + (float)q45.y*(float)kb45.y
                 + (float)q67.x*(float)kb67.x + (float)q67.y*(float)kb67.y;
#endif
        DPPADD(sd, 0xB1);   // quad xor1
        DPPADD(sd, 0x4E);   // quad xor2  -> head's 4-lane sum
        float es = __expf(sd);
        ssum += es;
        vac0 += es * (float)vb01.x; vac1 += es * (float)vb01.y;
        vac2 += es * (float)vb23.x; vac3 += es * (float)vb23.y;
        vac4 += es * (float)vb45.x; vac5 += es * (float)vb45.y;
        vac6 += es * (float)vb67.x; vac7 += es * (float)vb67.y;
    }
    const float inv = 1.f / (ssum * (float)NCAM);
    uint4 o;
    o.x = packrtz(vac0 * inv, vac1 * inv);
    o.y = packrtz(vac2 * inv, vac3 * inv);
    o.z = packrtz(vac4 * inv, vac5 * inv);
    o.w = packrtz(vac6 * inv, vac7 * inv);
    *(uint4*)&wbuf2[((size_t)s * 4096 + ql0 + q_l) * 128 + c * 8] = o;
}

// ---------------------------------------------------------------------------
// Output projection with 6-camera partial sum in the B^T stage.
// ---------------------------------------------------------------------------
__global__ __launch_bounds__(256) void sgemm_kernel(
    const float* __restrict__ A, const ushort_t* __restrict__ B2,
    const float* __restrict__ bias, float* __restrict__ C)
{
    __shared__ float As[16][68];
    __shared__ float Bs[16][68];
    const int z = blockIdx.z;
    float* Cb = C + (size_t)z * 128 * 4096;
    const int tid = threadIdx.x;
    const int bm = blockIdx.y * 64, bn = blockIdx.x * 64;
    const int tm = ((tid >> 4) & 15) << 2;
    const int tn = (tid & 15) << 2;

    float acc[4][4] = {};
    for (int k0 = 0; k0 < 128; k0 += 16) {
        #pragma unroll
        for (int i = 0; i < 4; ++i) {
            int idx = tid + i * 256;
            int mk = idx >> 4, kk = idx & 15;
            As[kk][mk] = A[(size_t)(bm + mk) * 128 + (k0 + kk)];
        }
        {
            int pxl = tid >> 2, kc = (tid & 3) * 4;
            float b0 = 0.f, b1 = 0.f, b2 = 0.f, b3 = 0.f;
            #pragma unroll
            for (int nn = 0; nn < 6; ++nn) {
                const ushort_t* src = B2 + (((size_t)(z*6+nn) * 4096 + bn + pxl) * 128 + k0 + kc);
                uint2 v = *(const uint2*)src;
                h2 h0 = u2h(v.x), h1 = u2h(v.y);
                b0 += (float)h0.x; b1 += (float)h0.y;
                b2 += (float)h1.x; b3 += (float)h1.y;
            }
            Bs[kc+0][pxl] = b0; Bs[kc+1][pxl] = b1;
            Bs[kc+2][pxl] = b2; Bs[kc+3][pxl] = b3;
        }
        __syncthreads();
        #pragma unroll
        for (int kk = 0; kk < 16; ++kk) {
            const float4 av = *(const float4*)&As[kk][tm];
            const float4 bv = *(const float4*)&Bs[kk][tn];
            const float a[4]  = {av.x, av.y, av.z, av.w};
            const float bb[4] = {bv.x, bv.y, bv.z, bv.w};
            #pragma unroll
            for (int i = 0; i < 4; ++i)
                #pragma unroll
                for (int j = 0; j < 4; ++j) acc[i][j] += a[i] * bb[j];
        }
        __syncthreads();
    }
    #pragma unroll
    for (int i = 0; i < 4; ++i) {
        int gm = bm + tm + i;
        float bi = bias[gm];
        float4 v = make_float4(acc[i][0]+bi, acc[i][1]+bi, acc[i][2]+bi, acc[i][3]+bi);
        *(float4*)&Cb[(size_t)gm * 4096 + (bn + tn)] = v;
    }
}

// ---------------------------------------------------------------------------
extern "C" void kernel_launch(void* const* d_in, const int* in_sizes, int n_in,
                              void* d_out, int out_size, void* d_ws, size_t ws_size,
                              hipStream_t stream)
{
    const float* bev   = (const float*)d_in[0];
    const float* img   = (const float*)d_in[1];
    const float* Kin   = (const float*)d_in[2];
    const float* Ein   = (const float*)d_in[3];
    const float* wxy   = (const float*)d_in[4];
    const float* wq    = (const float*)d_in[5];
    const float* bq    = (const float*)d_in[6];
    const float* wkv   = (const float*)d_in[7];
    const float* bkv   = (const float*)d_in[8];
    const float* woff1 = (const float*)d_in[9];
    const float* boff1 = (const float*)d_in[10];
    const float* woff2 = (const float*)d_in[11];
    const float* boff2 = (const float*)d_in[12];
    const float* wproj = (const float*)d_in[13];
    const float* bproj = (const float*)d_in[14];
    float* out = (float*)d_out;

    char* wsb = (char*)d_ws;
    ushort_t* kvb   = (ushort_t*)wsb;                       // 17,301,504 B
    ushort_t* qbb   = (ushort_t*)(wsb + 17301504);          //  2,097,152 B
    uint4*    sampb = (uint4*)   (wsb + 19398656);          //  6,291,456 B
    ushort_t* wbuf2 = (ushort_t*)(wsb + 25690112);          // 12,582,912 B

    bev_mlp<<<dim3(2*HWQ/16), 256, 0, stream>>>(
        bev, wq, bq, woff1, boff1, woff2, boff2, Ein, Kin, wxy, qbb, sampb);
    kv_mfma<<<dim3(528), 256, 0, stream>>>(wkv, img, bkv, kvb);
    attn_kernel<<<dim3(1536), 512, 0, stream>>>(kvb, qbb, sampb, wbuf2);
    sgemm_kernel<<<dim3(HWQ/64, 2, 2), 256, 0, stream>>>(wproj, wbuf2, bproj, out);
}